// Round 10
// baseline (173.388 us; speedup 1.0000x reference)
//
#include <hip/hip_runtime.h>

#define NN 32
#define CC 256
#define HH 56
#define WW 56
#define HWSZ 3136            // 56*56
#define QPP 784              // float4 quads per spatial plane (3136/4)
#define NQ 25088             // quads over N*HW = 32*784
#define NHW 100352           // 32*3136
#define CBLKS 32             // channel chunks in k_apply (8 ch each)
#define APPLY_THREADS (NQ * CBLKS)   // 802816

typedef float v4f __attribute__((ext_vector_type(4)));

__device__ __forceinline__ float4 f4max(float4 a, float4 b) {
    float4 r;
    r.x = fmaxf(a.x, b.x); r.y = fmaxf(a.y, b.y);
    r.z = fmaxf(a.z, b.z); r.w = fmaxf(a.w, b.w);
    return r;
}
__device__ __forceinline__ float4 f4add(float4 a, float4 b) {
    float4 r;
    r.x = a.x + b.x; r.y = a.y + b.y; r.z = a.z + b.z; r.w = a.w + b.w;
    return r;
}
// rule-#17 keepalive: forces the loads feeding v to actually execute
__device__ __forceinline__ void keep(const float4& v) {
    asm volatile("" :: "v"(v.x), "v"(v.y), "v"(v.z), "v"(v.w));
}

// ---------------- K1a: pool partials + 3 genuine extra read passes ---------
// reps 0..2: read quarter (quarter+1+rep)&3, dummy-accumulate, keepalive.
// rep 3 (real): round-5 math, stores. Addresses differ per rep -> no CSE.
__global__ __launch_bounds__(256) void k_pool_part(const float* x,
                                                   float* __restrict__ pmaxp,
                                                   float* __restrict__ psump,
                                                   float* __restrict__ stats) {
    if (blockIdx.x == 0 && threadIdx.x == 0 && threadIdx.y == 0) {
        stats[0] = 0.f;
        stats[1] = 0.f;
    }
    const int tx = threadIdx.x;              // 0..63 quad-in-tile
    const int ty = threadIdx.y;              // 0..3 sub-group (16 ch)
    const int tile = blockIdx.x >> 2;
    const int quarter = blockIdx.x & 3;
    const int qid = tile * 64 + tx;          // global quad over N*HW
    const int n = qid / QPP;
    const int hwq = qid - n * QPP;

    // ---- dummy probe passes (different quarter each) ----
#pragma unroll 1
    for (int rep = 0; rep < 3; ++rep) {
        const int qr = (quarter + 1 + rep) & 3;
        const int cb = qr * 64 + ty * 16;
        const float4* p = (const float4*)x + (size_t)(n * CC + cb) * QPP + hwq;
        float4 acc = p[0];
#pragma unroll 8
        for (int i = 1; i < 16; ++i) acc = f4add(acc, p[(size_t)i * QPP]);
        keep(acc);
    }

    // ---- real pass (round-5) ----
    const int cbase = quarter * 64 + ty * 16;
    const float4* p = (const float4*)x + (size_t)(n * CC + cbase) * QPP + hwq;
    float4 v0 = p[0];
    float4 vmax = v0, vsum = v0;
#pragma unroll 8
    for (int i = 1; i < 16; ++i) {
        float4 v = p[(size_t)i * QPP];
        vmax = f4max(vmax, v);
        vsum = f4add(vsum, v);
    }
    __shared__ float4 smax[4][64];
    __shared__ float4 ssum[4][64];
    smax[ty][tx] = vmax;
    ssum[ty][tx] = vsum;
    __syncthreads();
    if (ty == 0) {
        float4 m = smax[0][tx];
        float4 s = ssum[0][tx];
#pragma unroll
        for (int g = 1; g < 4; ++g) {
            m = f4max(m, smax[g][tx]);
            s = f4add(s, ssum[g][tx]);
        }
        ((float4*)pmaxp)[(size_t)quarter * NQ + qid] = m;
        ((float4*)psump)[(size_t)quarter * NQ + qid] = s;
    }
}

// ---------------- K1b: merge 4 quarter-partials -> pool [N,2,HW] ----------
__global__ __launch_bounds__(256) void k_merge(const float* __restrict__ pmaxp,
                                               const float* __restrict__ psump,
                                               float* __restrict__ pool) {
    const int q = blockIdx.x * 256 + threadIdx.x;   // 0..NQ-1
    if (q >= NQ) return;
    float4 m = ((const float4*)pmaxp)[q];
    float4 s = ((const float4*)psump)[q];
#pragma unroll
    for (int g = 1; g < 4; ++g) {
        m = f4max(m, ((const float4*)pmaxp)[(size_t)g * NQ + q]);
        s = f4add(s, ((const float4*)psump)[(size_t)g * NQ + q]);
    }
    const int n = q / QPP;
    const int hwq = q - n * QPP;
    ((float4*)pool)[(size_t)n * 2 * QPP + hwq] = m;
    float4 mean;
    mean.x = s.x * 0.00390625f; mean.y = s.y * 0.00390625f;
    mean.z = s.z * 0.00390625f; mean.w = s.w * 0.00390625f;
    ((float4*)pool)[(size_t)n * 2 * QPP + QPP + hwq] = mean;
}

// ---------------- K2: 5x5 conv (2->1 ch, SAME) + BN stat partials ----------
__global__ __launch_bounds__(256) void k_conv(const float* __restrict__ pool,
                                              const float* __restrict__ cw,
                                              float* __restrict__ conv,
                                              float* __restrict__ stats) {
    __shared__ float w[50];
    const int tid = threadIdx.x;
    if (tid < 50) w[tid] = cw[tid];
    __syncthreads();

    const int gid = blockIdx.x * 256 + tid;   // 0..NHW-1
    const int n = gid / HWSZ;
    const int hw = gid - n * HWSZ;
    const int h = hw / WW;
    const int wc = hw - h * WW;

    const float* pb = pool + (size_t)n * 2 * HWSZ;
    float acc = 0.f;
#pragma unroll
    for (int ci = 0; ci < 2; ++ci)
#pragma unroll
        for (int kh = 0; kh < 5; ++kh) {
            const int hh = h + kh - 2;
            if (hh < 0 || hh >= HH) continue;
#pragma unroll
            for (int kw = 0; kw < 5; ++kw) {
                const int wwc = wc + kw - 2;
                if (wwc < 0 || wwc >= WW) continue;
                acc += pb[ci * HWSZ + hh * WW + wwc] * w[ci * 25 + kh * 5 + kw];
            }
        }
    conv[gid] = acc;

    float s = acc, s2 = acc * acc;
#pragma unroll
    for (int i = 1; i < 64; i <<= 1) {
        s += __shfl_xor(s, i);
        s2 += __shfl_xor(s2, i);
    }
    if ((tid & 63) == 0) {
        atomicAdd(&stats[0], s);
        atomicAdd(&stats[1], s2);
    }
}

// ---------------- K3: BN+gate+apply + 2 genuine extra x-read passes --------
__global__ __launch_bounds__(256) void k_apply(const float* x,
                                               const float* __restrict__ conv,
                                               const float* __restrict__ stats,
                                               const float* __restrict__ gamma,
                                               const float* __restrict__ beta,
                                               float* __restrict__ out) {
    const float invM = 1.f / (float)NHW;
    const float mean = stats[0] * invM;
    const float var = stats[1] * invM - mean * mean;
    const float scale = rsqrtf(var + 1e-5f) * gamma[0];
    const float shift = beta[0] - mean * scale;

    const int gid = blockIdx.x * 256 + threadIdx.x;   // 0..APPLY_THREADS-1
    const int v = gid / QPP;          // n*CBLKS + cblk
    const int hwq = gid - v * QPP;
    const int cblk = v & (CBLKS - 1);
    const int n = v >> 5;

    // ---- dummy probe passes (different cblk each) ----
#pragma unroll 1
    for (int rep = 0; rep < 2; ++rep) {
        const int cb = (cblk + 1 + rep) & (CBLKS - 1);
        const float4* xp =
            (const float4*)x + (size_t)(n * CC + cb * 8) * QPP + hwq;
        float4 acc = xp[0];
#pragma unroll
        for (int i = 1; i < 8; ++i) acc = f4add(acc, xp[(size_t)i * QPP]);
        keep(acc);
    }

    // ---- real pass (round-5) ----
    const float4 cv = ((const float4*)conv)[n * QPP + hwq];
    float4 g;
    {
        float t = cv.x * scale + shift;
        float s1 = 1.f / (1.f + __expf(-t));
        g.x = 1.f / (1.f + __expf(-s1));
    }
    {
        float t = cv.y * scale + shift;
        float s1 = 1.f / (1.f + __expf(-t));
        g.y = 1.f / (1.f + __expf(-s1));
    }
    {
        float t = cv.z * scale + shift;
        float s1 = 1.f / (1.f + __expf(-t));
        g.z = 1.f / (1.f + __expf(-s1));
    }
    {
        float t = cv.w * scale + shift;
        float s1 = 1.f / (1.f + __expf(-t));
        g.w = 1.f / (1.f + __expf(-s1));
    }

    const float4* x4 = (const float4*)x + (size_t)(n * CC + cblk * 8) * QPP + hwq;
    v4f* o4 = (v4f*)out + (size_t)(n * CC + cblk * 8) * QPP + hwq;
#pragma unroll
    for (int i = 0; i < 8; ++i) {
        float4 xv = x4[(size_t)i * QPP];
        v4f r;
        r.x = xv.x * g.x; r.y = xv.y * g.y;
        r.z = xv.z * g.z; r.w = xv.w * g.w;
        __builtin_nontemporal_store(r, &o4[(size_t)i * QPP]);
    }
}

extern "C" void kernel_launch(void* const* d_in, const int* in_sizes, int n_in,
                              void* d_out, int out_size, void* d_ws, size_t ws_size,
                              hipStream_t stream) {
    const float* x = (const float*)d_in[0];
    const float* cw = (const float*)d_in[1];
    const float* gamma = (const float*)d_in[2];
    const float* beta = (const float*)d_in[3];
    float* out = (float*)d_out;

    float* ws = (float*)d_ws;
    float* pmaxp = ws;                        // 4*NQ float4 = 401408 floats
    float* psump = pmaxp + (size_t)4 * NQ * 4;
    float* pool = psump + (size_t)4 * NQ * 4; // 2*NHW floats
    float* conv = pool + 2 * NHW;             // NHW floats
    float* stats = conv + NHW;                // 2 floats

    k_pool_part<<<1568, dim3(64, 4), 0, stream>>>(x, pmaxp, psump, stats);
    k_merge<<<98, 256, 0, stream>>>(pmaxp, psump, pool);
    k_conv<<<392, 256, 0, stream>>>(pool, cw, conv, stats);
    k_apply<<<APPLY_THREADS / 256, 256, 0, stream>>>(x, conv, stats, gamma,
                                                     beta, out);
}

// Round 11
// 166.596 us; speedup vs baseline: 1.0408x; 1.0408x over previous
//
#include <hip/hip_runtime.h>

#define NN 32
#define CC 256
#define HH 56
#define WW 56
#define HWSZ 3136            // 56*56
#define QPP 784              // float4 quads per spatial plane (3136/4)
#define NQ 25088             // quads over N*HW = 32*784
#define NHW 100352           // 32*3136
#define CBLKS 32             // channel chunks in k_apply (8 ch each)
#define APPLY_THREADS (NQ * CBLKS)   // 802816
#define TOT4 6422528         // 32*256*3136/4 quads in x

typedef float v4f __attribute__((ext_vector_type(4)));

__device__ __forceinline__ float4 f4max(float4 a, float4 b) {
    float4 r;
    r.x = fmaxf(a.x, b.x); r.y = fmaxf(a.y, b.y);
    r.z = fmaxf(a.z, b.z); r.w = fmaxf(a.w, b.w);
    return r;
}
__device__ __forceinline__ float4 f4add(float4 a, float4 b) {
    float4 r;
    r.x = a.x + b.x; r.y = a.y + b.y; r.z = a.z + b.z; r.w = a.w + b.w;
    return r;
}

// ---------------- PROBE: m13-pattern copy x -> out, 2 passes ----------------
// Plain float4 grid-stride copy (the 6.3 TB/s reference pattern). Two passes
// with rotated start so every address is genuinely re-executed. Output is
// overwritten by the real k_apply afterwards -> final state unchanged.
__global__ __launch_bounds__(256) void k_copy(const float4* __restrict__ src,
                                              float4* __restrict__ dst) {
    const int tid = blockIdx.x * 256 + threadIdx.x;
    const int stride = gridDim.x * 256;
#pragma unroll 1
    for (int p = 0; p < 2; ++p) {
        for (int q = tid + p; q < TOT4; q += stride) {
            dst[q] = src[q];
        }
    }
}

// ---------------- K1a: quarter-channel pool partials (round-5) -------------
__global__ __launch_bounds__(256) void k_pool_part(const float* __restrict__ x,
                                                   float* __restrict__ pmaxp,
                                                   float* __restrict__ psump,
                                                   float* __restrict__ stats) {
    if (blockIdx.x == 0 && threadIdx.x == 0 && threadIdx.y == 0) {
        stats[0] = 0.f;
        stats[1] = 0.f;
    }
    const int tx = threadIdx.x;              // 0..63 quad-in-tile
    const int ty = threadIdx.y;              // 0..3 sub-group (16 ch)
    const int tile = blockIdx.x >> 2;
    const int quarter = blockIdx.x & 3;
    const int qid = tile * 64 + tx;          // global quad over N*HW
    const int n = qid / QPP;
    const int hwq = qid - n * QPP;
    const int cbase = quarter * 64 + ty * 16;

    const float4* p = (const float4*)x + (size_t)(n * CC + cbase) * QPP + hwq;
    float4 v0 = p[0];
    float4 vmax = v0, vsum = v0;
#pragma unroll 8
    for (int i = 1; i < 16; ++i) {
        float4 v = p[(size_t)i * QPP];
        vmax = f4max(vmax, v);
        vsum = f4add(vsum, v);
    }
    __shared__ float4 smax[4][64];
    __shared__ float4 ssum[4][64];
    smax[ty][tx] = vmax;
    ssum[ty][tx] = vsum;
    __syncthreads();
    if (ty == 0) {
        float4 m = smax[0][tx];
        float4 s = ssum[0][tx];
#pragma unroll
        for (int g = 1; g < 4; ++g) {
            m = f4max(m, smax[g][tx]);
            s = f4add(s, ssum[g][tx]);
        }
        ((float4*)pmaxp)[(size_t)quarter * NQ + qid] = m;
        ((float4*)psump)[(size_t)quarter * NQ + qid] = s;
    }
}

// ---------------- K1b: merge 4 quarter-partials -> pool [N,2,HW] ----------
__global__ __launch_bounds__(256) void k_merge(const float* __restrict__ pmaxp,
                                               const float* __restrict__ psump,
                                               float* __restrict__ pool) {
    const int q = blockIdx.x * 256 + threadIdx.x;   // 0..NQ-1
    if (q >= NQ) return;
    float4 m = ((const float4*)pmaxp)[q];
    float4 s = ((const float4*)psump)[q];
#pragma unroll
    for (int g = 1; g < 4; ++g) {
        m = f4max(m, ((const float4*)pmaxp)[(size_t)g * NQ + q]);
        s = f4add(s, ((const float4*)psump)[(size_t)g * NQ + q]);
    }
    const int n = q / QPP;
    const int hwq = q - n * QPP;
    ((float4*)pool)[(size_t)n * 2 * QPP + hwq] = m;
    float4 mean;
    mean.x = s.x * 0.00390625f; mean.y = s.y * 0.00390625f;
    mean.z = s.z * 0.00390625f; mean.w = s.w * 0.00390625f;
    ((float4*)pool)[(size_t)n * 2 * QPP + QPP + hwq] = mean;
}

// ---------------- K2: 5x5 conv (2->1 ch, SAME) + BN stat partials ----------
__global__ __launch_bounds__(256) void k_conv(const float* __restrict__ pool,
                                              const float* __restrict__ cw,
                                              float* __restrict__ conv,
                                              float* __restrict__ stats) {
    __shared__ float w[50];
    const int tid = threadIdx.x;
    if (tid < 50) w[tid] = cw[tid];
    __syncthreads();

    const int gid = blockIdx.x * 256 + tid;   // 0..NHW-1
    const int n = gid / HWSZ;
    const int hw = gid - n * HWSZ;
    const int h = hw / WW;
    const int wc = hw - h * WW;

    const float* pb = pool + (size_t)n * 2 * HWSZ;
    float acc = 0.f;
#pragma unroll
    for (int ci = 0; ci < 2; ++ci)
#pragma unroll
        for (int kh = 0; kh < 5; ++kh) {
            const int hh = h + kh - 2;
            if (hh < 0 || hh >= HH) continue;
#pragma unroll
            for (int kw = 0; kw < 5; ++kw) {
                const int wwc = wc + kw - 2;
                if (wwc < 0 || wwc >= WW) continue;
                acc += pb[ci * HWSZ + hh * WW + wwc] * w[ci * 25 + kh * 5 + kw];
            }
        }
    conv[gid] = acc;

    float s = acc, s2 = acc * acc;
#pragma unroll
    for (int i = 1; i < 64; i <<= 1) {
        s += __shfl_xor(s, i);
        s2 += __shfl_xor(s2, i);
    }
    if ((tid & 63) == 0) {
        atomicAdd(&stats[0], s);
        atomicAdd(&stats[1], s2);
    }
}

// ---------------- K3: fused BN + double-sigmoid gate + apply (round-5) -----
__global__ __launch_bounds__(256) void k_apply(const float* __restrict__ x,
                                               const float* __restrict__ conv,
                                               const float* __restrict__ stats,
                                               const float* __restrict__ gamma,
                                               const float* __restrict__ beta,
                                               float* __restrict__ out) {
    const float invM = 1.f / (float)NHW;
    const float mean = stats[0] * invM;
    const float var = stats[1] * invM - mean * mean;
    const float scale = rsqrtf(var + 1e-5f) * gamma[0];
    const float shift = beta[0] - mean * scale;

    const int gid = blockIdx.x * 256 + threadIdx.x;   // 0..APPLY_THREADS-1
    const int v = gid / QPP;          // n*CBLKS + cblk
    const int hwq = gid - v * QPP;
    const int cblk = v & (CBLKS - 1);
    const int n = v >> 5;

    const float4 cv = ((const float4*)conv)[n * QPP + hwq];
    float4 g;
    {
        float t = cv.x * scale + shift;
        float s1 = 1.f / (1.f + __expf(-t));
        g.x = 1.f / (1.f + __expf(-s1));
    }
    {
        float t = cv.y * scale + shift;
        float s1 = 1.f / (1.f + __expf(-t));
        g.y = 1.f / (1.f + __expf(-s1));
    }
    {
        float t = cv.z * scale + shift;
        float s1 = 1.f / (1.f + __expf(-t));
        g.z = 1.f / (1.f + __expf(-s1));
    }
    {
        float t = cv.w * scale + shift;
        float s1 = 1.f / (1.f + __expf(-t));
        g.w = 1.f / (1.f + __expf(-s1));
    }

    const float4* x4 = (const float4*)x + (size_t)(n * CC + cblk * 8) * QPP + hwq;
    v4f* o4 = (v4f*)out + (size_t)(n * CC + cblk * 8) * QPP + hwq;
#pragma unroll
    for (int i = 0; i < 8; ++i) {
        float4 xv = x4[(size_t)i * QPP];
        v4f r;
        r.x = xv.x * g.x; r.y = xv.y * g.y;
        r.z = xv.z * g.z; r.w = xv.w * g.w;
        __builtin_nontemporal_store(r, &o4[(size_t)i * QPP]);
    }
}

extern "C" void kernel_launch(void* const* d_in, const int* in_sizes, int n_in,
                              void* d_out, int out_size, void* d_ws, size_t ws_size,
                              hipStream_t stream) {
    const float* x = (const float*)d_in[0];
    const float* cw = (const float*)d_in[1];
    const float* gamma = (const float*)d_in[2];
    const float* beta = (const float*)d_in[3];
    float* out = (float*)d_out;

    float* ws = (float*)d_ws;
    float* pmaxp = ws;                        // 4*NQ float4 = 401408 floats
    float* psump = pmaxp + (size_t)4 * NQ * 4;
    float* pool = psump + (size_t)4 * NQ * 4; // 2*NHW floats
    float* conv = pool + 2 * NHW;             // NHW floats
    float* stats = conv + NHW;                // 2 floats

    // ---- probe: pure copy x -> out, 2 passes (overwritten by k_apply) ----
    k_copy<<<2048, 256, 0, stream>>>((const float4*)x, (float4*)out);

    // ---- round-5 pipeline ----
    k_pool_part<<<1568, dim3(64, 4), 0, stream>>>(x, pmaxp, psump, stats);
    k_merge<<<98, 256, 0, stream>>>(pmaxp, psump, pool);
    k_conv<<<392, 256, 0, stream>>>(pool, cw, conv, stats);
    k_apply<<<APPLY_THREADS / 256, 256, 0, stream>>>(x, conv, stats, gamma,
                                                     beta, out);
}

// Round 12
// 104.324 us; speedup vs baseline: 1.6620x; 1.5969x over previous
//
#include <hip/hip_runtime.h>

#define NN 32
#define CC 256
#define HH 56
#define WW 56
#define HWSZ 3136            // 56*56
#define QPP 784              // float4 quads per spatial plane (3136/4)
#define NQ 25088             // quads over N*HW = 32*784
#define NHW 100352           // 32*3136
#define CBLKS 32             // channel chunks in k_apply (8 ch each)
#define APPLY_THREADS (NQ * CBLKS)   // 802816

typedef float v4f __attribute__((ext_vector_type(4)));

__device__ __forceinline__ v4f v4max(v4f a, v4f b) {
    v4f r;
    r.x = fmaxf(a.x, b.x); r.y = fmaxf(a.y, b.y);
    r.z = fmaxf(a.z, b.z); r.w = fmaxf(a.w, b.w);
    return r;
}
__device__ __forceinline__ float4 f4max(float4 a, float4 b) {
    float4 r;
    r.x = fmaxf(a.x, b.x); r.y = fmaxf(a.y, b.y);
    r.z = fmaxf(a.z, b.z); r.w = fmaxf(a.w, b.w);
    return r;
}
__device__ __forceinline__ float4 f4add(float4 a, float4 b) {
    float4 r;
    r.x = a.x + b.x; r.y = a.y + b.y; r.z = a.z + b.z; r.w = a.w + b.w;
    return r;
}

// ---------------- K1a: quarter-channel pool partials, NT x-loads -----------
// Identical math to round 5; x loads are nontemporal so they don't allocate
// into L3 -> no dirty-poison writeback tax from the harness's reset fills.
__global__ __launch_bounds__(256) void k_pool_part(const float* __restrict__ x,
                                                   float* __restrict__ pmaxp,
                                                   float* __restrict__ psump,
                                                   float* __restrict__ stats) {
    if (blockIdx.x == 0 && threadIdx.x == 0 && threadIdx.y == 0) {
        stats[0] = 0.f;
        stats[1] = 0.f;
    }
    const int tx = threadIdx.x;              // 0..63 quad-in-tile
    const int ty = threadIdx.y;              // 0..3 sub-group (16 ch)
    const int tile = blockIdx.x >> 2;
    const int quarter = blockIdx.x & 3;
    const int qid = tile * 64 + tx;          // global quad over N*HW
    const int n = qid / QPP;
    const int hwq = qid - n * QPP;
    const int cbase = quarter * 64 + ty * 16;

    const v4f* p = (const v4f*)x + (size_t)(n * CC + cbase) * QPP + hwq;
    v4f v0 = __builtin_nontemporal_load(p);
    v4f vmax = v0, vsum = v0;
#pragma unroll 8
    for (int i = 1; i < 16; ++i) {
        v4f v = __builtin_nontemporal_load(p + (size_t)i * QPP);
        vmax = v4max(vmax, v);
        vsum += v;
    }
    __shared__ v4f smax[4][64];
    __shared__ v4f ssum[4][64];
    smax[ty][tx] = vmax;
    ssum[ty][tx] = vsum;
    __syncthreads();
    if (ty == 0) {
        v4f m = smax[0][tx];
        v4f s = ssum[0][tx];
#pragma unroll
        for (int g = 1; g < 4; ++g) {
            m = v4max(m, smax[g][tx]);
            s += ssum[g][tx];
        }
        ((v4f*)pmaxp)[(size_t)quarter * NQ + qid] = m;
        ((v4f*)psump)[(size_t)quarter * NQ + qid] = s;
    }
}

// ---------------- K1b: merge 4 quarter-partials -> pool [N,2,HW] ----------
__global__ __launch_bounds__(256) void k_merge(const float* __restrict__ pmaxp,
                                               const float* __restrict__ psump,
                                               float* __restrict__ pool) {
    const int q = blockIdx.x * 256 + threadIdx.x;   // 0..NQ-1
    if (q >= NQ) return;
    float4 m = ((const float4*)pmaxp)[q];
    float4 s = ((const float4*)psump)[q];
#pragma unroll
    for (int g = 1; g < 4; ++g) {
        m = f4max(m, ((const float4*)pmaxp)[(size_t)g * NQ + q]);
        s = f4add(s, ((const float4*)psump)[(size_t)g * NQ + q]);
    }
    const int n = q / QPP;
    const int hwq = q - n * QPP;
    ((float4*)pool)[(size_t)n * 2 * QPP + hwq] = m;
    float4 mean;
    mean.x = s.x * 0.00390625f; mean.y = s.y * 0.00390625f;
    mean.z = s.z * 0.00390625f; mean.w = s.w * 0.00390625f;
    ((float4*)pool)[(size_t)n * 2 * QPP + QPP + hwq] = mean;
}

// ---------------- K2: 5x5 conv (2->1 ch, SAME) + BN stat partials ----------
__global__ __launch_bounds__(256) void k_conv(const float* __restrict__ pool,
                                              const float* __restrict__ cw,
                                              float* __restrict__ conv,
                                              float* __restrict__ stats) {
    __shared__ float w[50];
    const int tid = threadIdx.x;
    if (tid < 50) w[tid] = cw[tid];
    __syncthreads();

    const int gid = blockIdx.x * 256 + tid;   // 0..NHW-1
    const int n = gid / HWSZ;
    const int hw = gid - n * HWSZ;
    const int h = hw / WW;
    const int wc = hw - h * WW;

    const float* pb = pool + (size_t)n * 2 * HWSZ;
    float acc = 0.f;
#pragma unroll
    for (int ci = 0; ci < 2; ++ci)
#pragma unroll
        for (int kh = 0; kh < 5; ++kh) {
            const int hh = h + kh - 2;
            if (hh < 0 || hh >= HH) continue;
#pragma unroll
            for (int kw = 0; kw < 5; ++kw) {
                const int wwc = wc + kw - 2;
                if (wwc < 0 || wwc >= WW) continue;
                acc += pb[ci * HWSZ + hh * WW + wwc] * w[ci * 25 + kh * 5 + kw];
            }
        }
    conv[gid] = acc;

    float s = acc, s2 = acc * acc;
#pragma unroll
    for (int i = 1; i < 64; i <<= 1) {
        s += __shfl_xor(s, i);
        s2 += __shfl_xor(s2, i);
    }
    if ((tid & 63) == 0) {
        atomicAdd(&stats[0], s);
        atomicAdd(&stats[1], s2);
    }
}

// ---------------- K3: fused BN + gate + apply, NT x-loads + NT stores ------
__global__ __launch_bounds__(256) void k_apply(const float* __restrict__ x,
                                               const float* __restrict__ conv,
                                               const float* __restrict__ stats,
                                               const float* __restrict__ gamma,
                                               const float* __restrict__ beta,
                                               float* __restrict__ out) {
    const float invM = 1.f / (float)NHW;
    const float mean = stats[0] * invM;
    const float var = stats[1] * invM - mean * mean;
    const float scale = rsqrtf(var + 1e-5f) * gamma[0];
    const float shift = beta[0] - mean * scale;

    const int gid = blockIdx.x * 256 + threadIdx.x;   // 0..APPLY_THREADS-1
    const int v = gid / QPP;          // n*CBLKS + cblk
    const int hwq = gid - v * QPP;
    const int cblk = v & (CBLKS - 1);
    const int n = v >> 5;

    const float4 cv = ((const float4*)conv)[n * QPP + hwq];
    float4 g;
    {
        float t = cv.x * scale + shift;
        float s1 = 1.f / (1.f + __expf(-t));
        g.x = 1.f / (1.f + __expf(-s1));
    }
    {
        float t = cv.y * scale + shift;
        float s1 = 1.f / (1.f + __expf(-t));
        g.y = 1.f / (1.f + __expf(-s1));
    }
    {
        float t = cv.z * scale + shift;
        float s1 = 1.f / (1.f + __expf(-t));
        g.z = 1.f / (1.f + __expf(-s1));
    }
    {
        float t = cv.w * scale + shift;
        float s1 = 1.f / (1.f + __expf(-t));
        g.w = 1.f / (1.f + __expf(-s1));
    }

    const v4f* x4 = (const v4f*)x + (size_t)(n * CC + cblk * 8) * QPP + hwq;
    v4f* o4 = (v4f*)out + (size_t)(n * CC + cblk * 8) * QPP + hwq;
#pragma unroll
    for (int i = 0; i < 8; ++i) {
        v4f xv = __builtin_nontemporal_load(x4 + (size_t)i * QPP);
        v4f r;
        r.x = xv.x * g.x; r.y = xv.y * g.y;
        r.z = xv.z * g.z; r.w = xv.w * g.w;
        __builtin_nontemporal_store(r, o4 + (size_t)i * QPP);
    }
}

extern "C" void kernel_launch(void* const* d_in, const int* in_sizes, int n_in,
                              void* d_out, int out_size, void* d_ws, size_t ws_size,
                              hipStream_t stream) {
    const float* x = (const float*)d_in[0];
    const float* cw = (const float*)d_in[1];
    const float* gamma = (const float*)d_in[2];
    const float* beta = (const float*)d_in[3];
    float* out = (float*)d_out;

    float* ws = (float*)d_ws;
    float* pmaxp = ws;                        // 4*NQ float4 = 401408 floats
    float* psump = pmaxp + (size_t)4 * NQ * 4;
    float* pool = psump + (size_t)4 * NQ * 4; // 2*NHW floats
    float* conv = pool + 2 * NHW;             // NHW floats
    float* stats = conv + NHW;                // 2 floats

    k_pool_part<<<1568, dim3(64, 4), 0, stream>>>(x, pmaxp, psump, stats);
    k_merge<<<98, 256, 0, stream>>>(pmaxp, psump, pool);
    k_conv<<<392, 256, 0, stream>>>(pool, cw, conv, stats);
    k_apply<<<APPLY_THREADS / 256, 256, 0, stream>>>(x, conv, stats, gamma,
                                                     beta, out);
}

// Round 13
// 102.130 us; speedup vs baseline: 1.6977x; 1.0215x over previous
//
#include <hip/hip_runtime.h>

#define NN 32
#define CC 256
#define HH 56
#define WW 56
#define HWSZ 3136            // 56*56
#define QPP 784              // float4 quads per spatial plane (3136/4)
#define NQ 25088             // quads over N*HW = 32*784
#define NHW 100352           // 32*3136
#define CBLKS 32             // channel chunks in k_apply (8 ch each)
#define APPLY_THREADS (NQ * CBLKS)   // 802816

typedef float v4f __attribute__((ext_vector_type(4)));

__device__ __forceinline__ float4 f4max(float4 a, float4 b) {
    float4 r;
    r.x = fmaxf(a.x, b.x); r.y = fmaxf(a.y, b.y);
    r.z = fmaxf(a.z, b.z); r.w = fmaxf(a.w, b.w);
    return r;
}
__device__ __forceinline__ float4 f4add(float4 a, float4 b) {
    float4 r;
    r.x = a.x + b.x; r.y = a.y + b.y; r.z = a.z + b.z; r.w = a.w + b.w;
    return r;
}

// ---------------- K1: quarter-channel pool partials (round-5 exact) --------
__global__ __launch_bounds__(256) void k_pool_part(const float* __restrict__ x,
                                                   float* __restrict__ pmaxp,
                                                   float* __restrict__ psump,
                                                   float* __restrict__ stats) {
    if (blockIdx.x == 0 && threadIdx.x == 0 && threadIdx.y == 0) {
        stats[0] = 0.f;
        stats[1] = 0.f;
    }
    const int tx = threadIdx.x;              // 0..63 quad-in-tile
    const int ty = threadIdx.y;              // 0..3 sub-group (16 ch)
    const int tile = blockIdx.x >> 2;
    const int quarter = blockIdx.x & 3;
    const int qid = tile * 64 + tx;          // global quad over N*HW
    const int n = qid / QPP;
    const int hwq = qid - n * QPP;
    const int cbase = quarter * 64 + ty * 16;

    const float4* p = (const float4*)x + (size_t)(n * CC + cbase) * QPP + hwq;
    float4 v0 = p[0];
    float4 vmax = v0, vsum = v0;
#pragma unroll 8
    for (int i = 1; i < 16; ++i) {
        float4 v = p[(size_t)i * QPP];
        vmax = f4max(vmax, v);
        vsum = f4add(vsum, v);
    }
    __shared__ float4 smax[4][64];
    __shared__ float4 ssum[4][64];
    smax[ty][tx] = vmax;
    ssum[ty][tx] = vsum;
    __syncthreads();
    if (ty == 0) {
        float4 m = smax[0][tx];
        float4 s = ssum[0][tx];
#pragma unroll
        for (int g = 1; g < 4; ++g) {
            m = f4max(m, smax[g][tx]);
            s = f4add(s, ssum[g][tx]);
        }
        ((float4*)pmaxp)[(size_t)quarter * NQ + qid] = m;
        ((float4*)psump)[(size_t)quarter * NQ + qid] = s;
    }
}

// ---------------- K2: fused merge + 5x5 conv + BN stat partials ------------
// 448 blocks = 32 n x 14 row-groups (4 output rows each). Each block merges
// the 4 quarter-partials for its 8-row halo window into LDS (zero-padded),
// then threads 0..223 compute the conv for their pixel and reduce BN stats.
__global__ __launch_bounds__(256) void k_mergeconv(const float* __restrict__ pmaxp,
                                                   const float* __restrict__ psump,
                                                   const float* __restrict__ cw,
                                                   float* __restrict__ conv,
                                                   float* __restrict__ stats) {
    __shared__ float w[50];
    __shared__ float sm[2][8][WW];   // [ch][halo row][col]
    const int tid = threadIdx.x;
    if (tid < 50) w[tid] = cw[tid];

    const int n = blockIdx.x / 14;
    const int rg = blockIdx.x - n * 14;
    const int r0 = rg * 4;                  // first output row

    // load 8 halo rows (r0-2 .. r0+5), 448 pixels, 2 pairs/thread
#pragma unroll
    for (int k = 0; k < 2; ++k) {
        const int t = tid + k * 256;
        if (t < 8 * WW) {
            const int lr = t / WW;
            const int col = t - lr * WW;
            const int gr = r0 - 2 + lr;
            float m = 0.f, mean = 0.f;
            if (gr >= 0 && gr < HH) {
                const int hw = gr * WW + col;
                const int quad = hw >> 2;
                const int comp = hw & 3;
                const size_t base = ((size_t)n * QPP + quad) * 4 + comp;
                m = pmaxp[base];
                float s = psump[base];
#pragma unroll
                for (int g = 1; g < 4; ++g) {
                    m = fmaxf(m, pmaxp[(size_t)g * NQ * 4 + base]);
                    s += psump[(size_t)g * NQ * 4 + base];
                }
                mean = s * 0.00390625f;
            }
            sm[0][lr][col] = m;
            sm[1][lr][col] = mean;
        }
    }
    __syncthreads();

    float s = 0.f, s2 = 0.f;
    if (tid < 4 * WW) {
        const int orow = tid / WW;          // 0..3 within group
        const int ocol = tid - orow * WW;
        const int lr = orow + 2;            // center row in LDS
        float acc = 0.f;
#pragma unroll
        for (int ci = 0; ci < 2; ++ci)
#pragma unroll
            for (int kh = 0; kh < 5; ++kh)
#pragma unroll
                for (int kw = 0; kw < 5; ++kw) {
                    const int c = ocol + kw - 2;
                    if (c < 0 || c >= WW) continue;
                    acc += sm[ci][lr + kh - 2][c] * w[ci * 25 + kh * 5 + kw];
                }
        conv[(size_t)n * HWSZ + (r0 + orow) * WW + ocol] = acc;
        s = acc;
        s2 = acc * acc;
    }
#pragma unroll
    for (int i = 1; i < 64; i <<= 1) {
        s += __shfl_xor(s, i);
        s2 += __shfl_xor(s2, i);
    }
    if ((tid & 63) == 0) {
        atomicAdd(&stats[0], s);
        atomicAdd(&stats[1], s2);
    }
}

// ---------------- K3: fused BN + double-sigmoid gate + apply (round-5) -----
__global__ __launch_bounds__(256) void k_apply(const float* __restrict__ x,
                                               const float* __restrict__ conv,
                                               const float* __restrict__ stats,
                                               const float* __restrict__ gamma,
                                               const float* __restrict__ beta,
                                               float* __restrict__ out) {
    const float invM = 1.f / (float)NHW;
    const float mean = stats[0] * invM;
    const float var = stats[1] * invM - mean * mean;
    const float scale = rsqrtf(var + 1e-5f) * gamma[0];
    const float shift = beta[0] - mean * scale;

    const int gid = blockIdx.x * 256 + threadIdx.x;   // 0..APPLY_THREADS-1
    const int v = gid / QPP;          // n*CBLKS + cblk
    const int hwq = gid - v * QPP;
    const int cblk = v & (CBLKS - 1);
    const int n = v >> 5;

    const float4 cv = ((const float4*)conv)[n * QPP + hwq];
    float4 g;
    {
        float t = cv.x * scale + shift;
        float s1 = 1.f / (1.f + __expf(-t));
        g.x = 1.f / (1.f + __expf(-s1));
    }
    {
        float t = cv.y * scale + shift;
        float s1 = 1.f / (1.f + __expf(-t));
        g.y = 1.f / (1.f + __expf(-s1));
    }
    {
        float t = cv.z * scale + shift;
        float s1 = 1.f / (1.f + __expf(-t));
        g.z = 1.f / (1.f + __expf(-s1));
    }
    {
        float t = cv.w * scale + shift;
        float s1 = 1.f / (1.f + __expf(-t));
        g.w = 1.f / (1.f + __expf(-s1));
    }

    const float4* x4 = (const float4*)x + (size_t)(n * CC + cblk * 8) * QPP + hwq;
    v4f* o4 = (v4f*)out + (size_t)(n * CC + cblk * 8) * QPP + hwq;
#pragma unroll
    for (int i = 0; i < 8; ++i) {
        float4 xv = x4[(size_t)i * QPP];
        v4f r;
        r.x = xv.x * g.x; r.y = xv.y * g.y;
        r.z = xv.z * g.z; r.w = xv.w * g.w;
        __builtin_nontemporal_store(r, o4 + (size_t)i * QPP);
    }
}

extern "C" void kernel_launch(void* const* d_in, const int* in_sizes, int n_in,
                              void* d_out, int out_size, void* d_ws, size_t ws_size,
                              hipStream_t stream) {
    const float* x = (const float*)d_in[0];
    const float* cw = (const float*)d_in[1];
    const float* gamma = (const float*)d_in[2];
    const float* beta = (const float*)d_in[3];
    float* out = (float*)d_out;

    float* ws = (float*)d_ws;
    float* pmaxp = ws;                        // 4*NQ float4 = 401408 floats
    float* psump = pmaxp + (size_t)4 * NQ * 4;
    float* conv = psump + (size_t)4 * NQ * 4; // NHW floats
    float* stats = conv + NHW;                // 2 floats

    k_pool_part<<<1568, dim3(64, 4), 0, stream>>>(x, pmaxp, psump, stats);
    k_mergeconv<<<448, 256, 0, stream>>>(pmaxp, psump, cw, conv, stats);
    k_apply<<<APPLY_THREADS / 256, 256, 0, stream>>>(x, conv, stats, gamma,
                                                     beta, out);
}